// Round 17
// baseline (325.772 us; speedup 1.0000x reference)
//
#include <hip/hip_runtime.h>

typedef unsigned short ushort_t;
typedef unsigned int uint32;
typedef __bf16 bf16x8 __attribute__((ext_vector_type(8)));
typedef float f32x4 __attribute__((ext_vector_type(4)));
typedef uint32 u32x4 __attribute__((ext_vector_type(4)));
typedef uint32 u32x2 __attribute__((ext_vector_type(2)));

typedef __attribute__((address_space(3))) uint32 as3_u32;
typedef const __attribute__((address_space(1))) uint32 as1_u32c;

// async global->LDS, 16B per lane; LDS dest = wave-uniform base + lane*16
__device__ __forceinline__ void gl_lds16(const ushort_t* g, ushort_t* l) {
    __builtin_amdgcn_global_load_lds((as1_u32c*)g, (as3_u32*)l, 16, 0, 0);
}

__device__ __forceinline__ float bf2f(ushort_t u) {
    uint32 x = ((uint32)u) << 16;
    return __builtin_bit_cast(float, x);
}
__device__ __forceinline__ ushort_t f2bf(float f) {
    uint32 x = __builtin_bit_cast(uint32, f);
    x += 0x7fffu + ((x >> 16) & 1u);   // RNE
    return (ushort_t)(x >> 16);
}
__device__ __forceinline__ void ld4bf(const ushort_t* p, float* f) {
    const u32x2 w = *(const u32x2*)p;
    f[0] = bf2f((ushort_t)(w[0] & 0xffffu)); f[1] = bf2f((ushort_t)(w[0] >> 16));
    f[2] = bf2f((ushort_t)(w[1] & 0xffffu)); f[3] = bf2f((ushort_t)(w[1] >> 16));
}
__device__ __forceinline__ u32x2 pk4bf(const float* v) {
    u32x2 pk;
    pk[0] = (uint32)f2bf(v[0]) | ((uint32)f2bf(v[1]) << 16);
    pk[1] = (uint32)f2bf(v[2]) | ((uint32)f2bf(v[3]) << 16);
    return pk;
}

// per-block dtype sniff: read first 1KB of detect, count non-f32-like exponents
__device__ __forceinline__ bool sniff(const void* in0) {
    const uint32* s = (const uint32*)in0;
    const int lane = threadIdx.x & 63;
    int wd = 0;
    for (int c = 0; c < 4; c++) {
        const uint32 w = s[lane * 4 + c];
        const uint32 e = (w >> 7) & 0xFFu;
        wd += (e < 64u) || (e >= 192u);
    }
    for (int off = 32; off; off >>= 1) wd += __shfl_down(wd, off);
    return __shfl(wd, 0) > 32;
}

// ALL canon work in ONE launch (4609 blocks), dtype sniffed per-block
struct VecArgs { const void* s[14]; ushort_t* d[14]; int n[14]; };
struct WtArgs { const void* s[6]; ushort_t* d[6]; int R[6]; int C[6]; };
__global__ void canon_all(const void* __restrict__ dsrc, ushort_t* __restrict__ ddst,
                          const void* __restrict__ asrc, ushort_t* __restrict__ adst,
                          WtArgs wa, VecArgs va, int* __restrict__ flag) {
    const bool isf32 = sniff(dsrc);
    const int b = blockIdx.x;
    if (b < 3072) {
        const void* src; ushort_t* dst; long n; int b0, nb;
        if (b < 2048) { src = dsrc; dst = ddst; n = 16777216; b0 = b; nb = 2048; }
        else          { src = asrc; dst = adst; n = 4194304;  b0 = b - 2048; nb = 1024; }
        long i = ((long)b0 * 256 + threadIdx.x) * 16;
        const long stride = (long)nb * 256 * 16;
        if (isf32) {
            const float* s = (const float*)src;
            for (; i < n; i += stride) {
                const f32x4 a0 = *(const f32x4*)(s + i);
                const f32x4 a1 = *(const f32x4*)(s + i + 4);
                const f32x4 a2 = *(const f32x4*)(s + i + 8);
                const f32x4 a3 = *(const f32x4*)(s + i + 12);
                u32x4 o0, o1;
                o0[0] = (uint32)f2bf(a0[0]) | ((uint32)f2bf(a0[1]) << 16);
                o0[1] = (uint32)f2bf(a0[2]) | ((uint32)f2bf(a0[3]) << 16);
                o0[2] = (uint32)f2bf(a1[0]) | ((uint32)f2bf(a1[1]) << 16);
                o0[3] = (uint32)f2bf(a1[2]) | ((uint32)f2bf(a1[3]) << 16);
                o1[0] = (uint32)f2bf(a2[0]) | ((uint32)f2bf(a2[1]) << 16);
                o1[1] = (uint32)f2bf(a2[2]) | ((uint32)f2bf(a2[3]) << 16);
                o1[2] = (uint32)f2bf(a3[0]) | ((uint32)f2bf(a3[1]) << 16);
                o1[3] = (uint32)f2bf(a3[2]) | ((uint32)f2bf(a3[3]) << 16);
                *(u32x4*)(dst + i) = o0;
                *(u32x4*)(dst + i + 8) = o1;
            }
        } else {
            const ushort_t* s = (const ushort_t*)src;
            for (; i < n; i += stride) {
                const u32x4 v0 = *(const u32x4*)(s + i);
                const u32x4 v1 = *(const u32x4*)(s + i + 8);
                *(u32x4*)(dst + i) = v0;
                *(u32x4*)(dst + i + 8) = v1;
            }
        }
    } else if (b < 4608) {
        const int local = b - 3072;
        const int wsel = local >> 8;
        const int rem = local & 255;
        const int tr = rem >> 4, tc = rem & 15;
        const int R = wa.R[wsel], C = wa.C[wsel];
        if (tc * 32 >= C || tr * 32 >= R) return;
        __shared__ float s[32][33];
        const int t = threadIdx.x;
        const int r = t >> 3, c4 = (t & 7) * 4;
        const long sbase = (long)(tr * 32 + r) * C + tc * 32 + c4;
        if (isf32) {
            const float* S = (const float*)wa.s[wsel];
            const f32x4 v = *(const f32x4*)(S + sbase);
            for (int u = 0; u < 4; u++) s[r][c4 + u] = v[u];
        } else {
            const ushort_t* S = (const ushort_t*)wa.s[wsel];
            for (int u = 0; u < 4; u++) s[r][c4 + u] = bf2f(S[sbase + u]);
        }
        __syncthreads();
        float tv[4];
        for (int u = 0; u < 4; u++) tv[u] = s[c4 + u][r];
        *(u32x2*)(wa.d[wsel] + (long)(tc * 32 + r) * R + tr * 32 + c4) = pk4bf(tv);
    } else {
        if (threadIdx.x == 0) *flag = isf32 ? 1 : 0;
        const int t = threadIdx.x;
        for (int seg = 0; seg < 14; seg++) {
            const int n = va.n[seg];
            if (isf32) {
                const float* s = (const float*)va.s[seg];
                for (int i = t; i < n; i += 256) va.d[seg][i] = f2bf(s[i]);
            } else {
                const ushort_t* s = (const ushort_t*)va.s[seg];
                for (int i = t; i < n; i += 256) va.d[seg][i] = s[i];
            }
        }
    }
}

// reduce 16 bf16 split-K partial slices -> plain bf16 G (scale folded in).
// 512 blocks, 8 elems/thread: zz = b>>5 selects (matrix,batch).
__global__ void reduce_g_kernel(const ushort_t* __restrict__ P1,
                                const ushort_t* __restrict__ P2,
                                ushort_t* __restrict__ G1, ushort_t* __restrict__ G2) {
    const int bxv = blockIdx.x;
    const int zz = bxv >> 5;                    // 0..15
    const ushort_t* P = (zz < 8) ? P1 : P2;
    ushort_t* G    = (zz < 8) ? G1 : G2;
    const float alpha = (zz < 8) ? (1.f / 4096.f) : (1.f / 1024.f);
    const int b = zz & 7;
    const long off = ((long)(bxv & 31) * 256 + threadIdx.x) * 8;
    const ushort_t* base = P + (long)b * 16 * 65536 + off;
    float acc[8] = {0, 0, 0, 0, 0, 0, 0, 0};
    for (int kc = 0; kc < 16; kc++) {
        const ushort_t* s = base + (long)kc * 65536;
        float f0[4], f1[4];
        ld4bf(s, f0); ld4bf(s + 4, f1);
#pragma unroll
        for (int u = 0; u < 4; u++) { acc[u] += f0[u]; acc[4 + u] += f1[u]; }
    }
    float v0[4], v1[4];
#pragma unroll
    for (int u = 0; u < 4; u++) { v0[u] = acc[u] * alpha; v1[u] = acc[4 + u] * alpha; }
    u32x4 o;
    const u32x2 p0 = pk4bf(v0), p1 = pk4bf(v1);
    o[0] = p0[0]; o[1] = p0[1]; o[2] = p1[0]; o[3] = p1[1];
    *(u32x4*)(G + (long)b * 65536 + off) = o;
}

#define BM 128
#define BN 128
#define BK 32
#define LDSH (BM * BK)
#define NBUF 3
#define BIGN (1 << 30)
#define ALLM 0x3fffffff

enum { EPI_BIAS = 0, EPI_BIASR = 1, EPI_SCALE = 2, EPI_BN = 3, EPI_PART = 4 };

struct GP {
    const ushort_t* A; const ushort_t* B; void* Cv; ushort_t* CT;
    const ushort_t* bias; const ushort_t* gamma; const ushort_t* beta;
    const ushort_t* mean; const ushort_t* var; const ushort_t* res;
    long coff, sA, sB, sC;
    int K, lda, ldb, ldc, cnmax, ldT, bshift, mmask;
    float alpha;
};
struct GP2 { GP g[2]; };

// NT GEMM 128x128 (r6-proven): depth-3 rotating LDS pipeline, 1 barrier/K-step.
// EPI_PART stores bf16 partials. (mmask unused in this variant.)
template <int EPI, bool DYNOUT, bool DUALT, bool SWAP>
__global__ __launch_bounds__(256) void gemm_nt(GP2 ga, int ysplit, int zsplit,
                                               const int* __restrict__ flag)
{
    __shared__ __align__(16) ushort_t As[NBUF * LDSH];
    __shared__ __align__(16) ushort_t Bs[NBUF * LDSH];

    const bool isf32 = DYNOUT ? (*flag != 0) : false;

    const uint32 gx = gridDim.x, gy = gridDim.y;
    const uint32 nwg = gx * gy * gridDim.z;
    const uint32 lid = blockIdx.x + gx * (blockIdx.y + gy * blockIdx.z);
    const uint32 swz = (lid & 7u) * (nwg >> 3) + (lid >> 3);
    const uint32 bx = swz % gx, t1 = swz / gx;
    int by = (int)(t1 % gy), bz = (int)(t1 / gy);

    int sel = 0;
    if (by >= ysplit) { by -= ysplit; sel = 1; }
    if (bz >= zsplit) { bz -= zsplit; sel = 1; }
    const GP& p = ga.g[sel];

    const ushort_t* A = p.A + (long)bz * p.sA;
    const ushort_t* B = p.B + ((long)bz + (long)(by >> p.bshift)) * p.sB;
    const long cbase = p.coff + (long)bz * p.sC;
    const int lda = p.lda, ldb = p.ldb, ldc = p.ldc, K = p.K;

    const int tid  = threadIdx.x;
    const int lane = tid & 63;
    const int w    = tid >> 6;
    const int wr   = w >> 1, wc = w & 1;
    const int lr   = lane & 15, q = lane >> 4;

    const int m0 = by * BM;
    const int n0 = bx * BN;

    const int lrow = lane >> 2, lu = lane & 3;
    const int us = (lu ^ ((lrow >> 1) & 3)) * 8;
    const int ra0 = w * 32 + lrow, ra1 = w * 32 + 16 + lrow;
    const ushort_t* Ar0 = A + (long)(m0 + ra0) * lda + us;
    const ushort_t* Ar1 = A + (long)(m0 + ra1) * lda + us;
    const ushort_t* Br0 = B + (long)(n0 + ra0) * ldb + us;
    const ushort_t* Br1 = B + (long)(n0 + ra1) * ldb + us;
    ushort_t* sA0 = &As[(w * 2 + 0) * 512];
    ushort_t* sA1 = &As[(w * 2 + 1) * 512];
    ushort_t* sB0 = &Bs[(w * 2 + 0) * 512];
    ushort_t* sB1 = &Bs[(w * 2 + 1) * 512];

    const int swq = (q ^ ((lr >> 1) & 3)) * 8;

    f32x4 acc[4][4];
#pragma unroll
    for (int i = 0; i < 4; i++)
#pragma unroll
        for (int j = 0; j < 4; j++) acc[i][j] = (f32x4){0.f, 0.f, 0.f, 0.f};

    const int nt = K / BK;
    {
        gl_lds16(Ar0, sA0); gl_lds16(Ar1, sA1);
        gl_lds16(Br0, sB0); gl_lds16(Br1, sB1);
        if (nt > 1) {
            gl_lds16(Ar0 + BK, sA0 + LDSH); gl_lds16(Ar1 + BK, sA1 + LDSH);
            gl_lds16(Br0 + BK, sB0 + LDSH); gl_lds16(Br1 + BK, sB1 + LDSH);
        }
    }

    int c0 = 0, c2 = 2;
    for (int t = 0; t < nt; ++t) {
        if (t + 1 < nt) asm volatile("s_waitcnt vmcnt(4)" ::: "memory");
        else            asm volatile("s_waitcnt vmcnt(0)" ::: "memory");
        __builtin_amdgcn_s_barrier();
        __builtin_amdgcn_sched_barrier(0);

        if (t + 2 < nt) {
            const int nb = c2 * LDSH;
            const int kn = (t + 2) * BK;
            gl_lds16(Ar0 + kn, sA0 + nb); gl_lds16(Ar1 + kn, sA1 + nb);
            gl_lds16(Br0 + kn, sB0 + nb); gl_lds16(Br1 + kn, sB1 + nb);
        }
        __builtin_amdgcn_sched_barrier(0);

        const ushort_t* Ab = As + c0 * LDSH;
        const ushort_t* Bb = Bs + c0 * LDSH;
        bf16x8 af[4], bfr[4];
#pragma unroll
        for (int i = 0; i < 4; i++)
            af[i] = __builtin_bit_cast(bf16x8,
                *(const u32x4*)(&Ab[(wr * 64 + i * 16 + lr) * BK + swq]));
#pragma unroll
        for (int j = 0; j < 4; j++)
            bfr[j] = __builtin_bit_cast(bf16x8,
                *(const u32x4*)(&Bb[(wc * 64 + j * 16 + lr) * BK + swq]));
#pragma unroll
        for (int i = 0; i < 4; i++)
#pragma unroll
            for (int j = 0; j < 4; j++) {
                if constexpr (SWAP)
                    acc[i][j] = __builtin_amdgcn_mfma_f32_16x16x32_bf16(bfr[j], af[i], acc[i][j], 0, 0, 0);
                else
                    acc[i][j] = __builtin_amdgcn_mfma_f32_16x16x32_bf16(af[i], bfr[j], acc[i][j], 0, 0, 0);
            }
        __builtin_amdgcn_sched_barrier(0);

        c0 = (c0 + 1 == NBUF) ? 0 : c0 + 1;
        c2 = (c2 + 1 == NBUF) ? 0 : c2 + 1;
    }

    if constexpr (SWAP) {
#pragma unroll
        for (int j = 0; j < 4; j++) {
            const int coln = n0 + wc * 64 + j * 16 + q * 4;
#pragma unroll
            for (int i = 0; i < 4; i++) {
                const int row = m0 + wr * 64 + i * 16 + lr;
                const long off = cbase + (long)row * ldc + coln;
                float v[4];
#pragma unroll
                for (int r = 0; r < 4; r++) v[r] = acc[i][j][r];
                if constexpr (EPI == EPI_PART) {
                    *(u32x2*)((ushort_t*)p.Cv + off) = pk4bf(v);   // bf16 partials
                } else if constexpr (DYNOUT) {
                    if (isf32) *(f32x4*)((float*)p.Cv + off) = (f32x4){v[0], v[1], v[2], v[3]};
                    else       *(u32x2*)((ushort_t*)p.Cv + off) = pk4bf(v);
                } else {
                    *(u32x2*)((ushort_t*)p.Cv + off) = pk4bf(v);
                }
            }
        }
    } else {
        const bool doC = (n0 < p.cnmax);
#pragma unroll
        for (int j = 0; j < 4; j++) {
            const int col = n0 + wc * 64 + j * 16 + lr;
            float bs = 0.f;
            if constexpr (EPI == EPI_BIAS) bs = bf2f(p.bias[col]);
#pragma unroll
            for (int i = 0; i < 4; i++) {
                const int rowbase = m0 + wr * 64 + i * 16 + q * 4;
                ushort_t tmp[4];
#pragma unroll
                for (int r = 0; r < 4; r++) {
                    const int row = rowbase + r;
                    float v = acc[i][j][r];
                    if constexpr (EPI == EPI_BIAS) v += bs;
                    else if constexpr (EPI == EPI_BIASR) v += bf2f(p.bias[row]);
                    else if constexpr (EPI == EPI_SCALE) v *= p.alpha;
                    const long off = cbase + (long)row * ldc + col;
                    const ushort_t us2 = f2bf(v);
                    tmp[r] = us2;
                    if (doC) ((ushort_t*)p.Cv)[off] = us2;
                }
                if constexpr (DUALT) {
                    u32x2 pk;
                    pk[0] = (uint32)tmp[0] | ((uint32)tmp[1] << 16);
                    pk[1] = (uint32)tmp[2] | ((uint32)tmp[3] << 16);
                    *(u32x2*)(p.CT + (long)bz * p.sC + (long)col * p.ldT + rowbase) = pk;
                }
            }
        }
    }
}

// ---- NT GEMM 64x128: half-M tile, 24KB LDS -> 6 blocks/CU. ----
// Decode: bz = by>>bshift (offsets A/B/C by sA/sB/sC); m0 = (by&mmask)*64.
// Covers conv (bz=0), outputs (bz=batch for B panel), split-K partials
// (bz=slice; EPI_SCALE alpha=1 stores bf16 partials via SWAP epilogue).
#define LDSA64 (64 * 32)
#define LDSB64 (128 * 32)
template <int EPI, bool DYNOUT, bool DUALT, bool SWAP>
__global__ __launch_bounds__(256) void gemm_nt64(GP2 ga, int ysplit,
                                                 const int* __restrict__ flag)
{
    __shared__ __align__(16) ushort_t As[2 * LDSA64];
    __shared__ __align__(16) ushort_t Bs[2 * LDSB64];

    const bool isf32 = DYNOUT ? (*flag != 0) : false;

    const uint32 gx = gridDim.x, gy = gridDim.y;
    const uint32 nwg = gx * gy;
    const uint32 lid = blockIdx.x + gx * blockIdx.y;
    const uint32 swz = (lid & 7u) * (nwg >> 3) + (lid >> 3);
    const uint32 bx = swz % gx;
    int byf = (int)(swz / gx);

    int sel = 0;
    if (byf >= ysplit) { byf -= ysplit; sel = 1; }
    const GP& p = ga.g[sel];

    const int bz = byf >> p.bshift;
    const ushort_t* A = p.A + (long)bz * p.sA;
    const ushort_t* B = p.B + (long)bz * p.sB;
    const long cbase = p.coff + (long)bz * p.sC;
    const int lda = p.lda, ldb = p.ldb, ldc = p.ldc, K = p.K;

    const int tid  = threadIdx.x;
    const int lane = tid & 63;
    const int w    = tid >> 6;
    const int wc   = w;                      // 4 waves across N (32 cols each)
    const int lr   = lane & 15, q = lane >> 4;

    const int m0 = (byf & p.mmask) * 64;
    const int n0 = bx * BN;

    const int lrow = lane >> 2, lu = lane & 3;
    const int us = (lu ^ ((lrow >> 1) & 3)) * 8;          // source-side swizzle
    const ushort_t* ArS = A + (long)(m0 + w * 16 + lrow) * lda + us;
    const ushort_t* Br0 = B + (long)(n0 + w * 32 + lrow) * ldb + us;
    const ushort_t* Br1 = B + (long)(n0 + w * 32 + 16 + lrow) * ldb + us;
    ushort_t* sAw = &As[w * 512];
    ushort_t* sB0 = &Bs[(w * 2 + 0) * 512];
    ushort_t* sB1 = &Bs[(w * 2 + 1) * 512];

    const int swq = (q ^ ((lr >> 1) & 3)) * 8;            // read-side swizzle

    f32x4 acc[4][2];
#pragma unroll
    for (int i = 0; i < 4; i++)
#pragma unroll
        for (int j = 0; j < 2; j++) acc[i][j] = (f32x4){0.f, 0.f, 0.f, 0.f};

    const int nt = K / BK;
    gl_lds16(ArS, sAw);
    gl_lds16(Br0, sB0);
    gl_lds16(Br1, sB1);

    for (int t = 0; t < nt; ++t) {
        const int cur = t & 1;
        if (t + 1 < nt) {
            const int kn = (t + 1) * BK;
            const int nbA = (cur ^ 1) * LDSA64, nbB = (cur ^ 1) * LDSB64;
            gl_lds16(ArS + kn, sAw + nbA);
            gl_lds16(Br0 + kn, sB0 + nbB);
            gl_lds16(Br1 + kn, sB1 + nbB);
            asm volatile("s_waitcnt vmcnt(3)" ::: "memory");
        } else {
            asm volatile("s_waitcnt vmcnt(0)" ::: "memory");
        }
        __builtin_amdgcn_s_barrier();
        __builtin_amdgcn_sched_barrier(0);

        const ushort_t* Ab = As + cur * LDSA64;
        const ushort_t* Bb = Bs + cur * LDSB64;
        bf16x8 af[4], bfr[2];
#pragma unroll
        for (int i = 0; i < 4; i++)
            af[i] = __builtin_bit_cast(bf16x8,
                *(const u32x4*)(&Ab[(i * 16 + lr) * BK + swq]));
#pragma unroll
        for (int j = 0; j < 2; j++)
            bfr[j] = __builtin_bit_cast(bf16x8,
                *(const u32x4*)(&Bb[(wc * 32 + j * 16 + lr) * BK + swq]));
#pragma unroll
        for (int i = 0; i < 4; i++)
#pragma unroll
            for (int j = 0; j < 2; j++) {
                if constexpr (SWAP)
                    acc[i][j] = __builtin_amdgcn_mfma_f32_16x16x32_bf16(bfr[j], af[i], acc[i][j], 0, 0, 0);
                else
                    acc[i][j] = __builtin_amdgcn_mfma_f32_16x16x32_bf16(af[i], bfr[j], acc[i][j], 0, 0, 0);
            }
        __builtin_amdgcn_sched_barrier(0);
        asm volatile("" ::: "memory");
        __builtin_amdgcn_s_barrier();
    }

    if constexpr (SWAP) {
#pragma unroll
        for (int j = 0; j < 2; j++) {
            const int coln = n0 + wc * 32 + j * 16 + q * 4;
            float sc4[4], sh4[4];
            if constexpr (EPI == EPI_BN) {
                float bb[4], g[4], bt[4], mn[4], vr[4];
                ld4bf(p.bias + coln, bb); ld4bf(p.gamma + coln, g); ld4bf(p.beta + coln, bt);
                ld4bf(p.mean + coln, mn); ld4bf(p.var + coln, vr);
#pragma unroll
                for (int r = 0; r < 4; r++) {
                    const float s = g[r] * rsqrtf(vr[r] + 1e-3f);
                    sc4[r] = s;
                    sh4[r] = s * bb[r] + bt[r] - s * mn[r];
                }
            } else if constexpr (EPI == EPI_BIAS) {
                float bb[4]; ld4bf(p.bias + coln, bb);
#pragma unroll
                for (int r = 0; r < 4; r++) { sc4[r] = 1.f; sh4[r] = bb[r]; }
            } else {
#pragma unroll
                for (int r = 0; r < 4; r++) { sc4[r] = p.alpha; sh4[r] = 0.f; }
            }
#pragma unroll
            for (int i = 0; i < 4; i++) {
                const int row = m0 + i * 16 + lr;
                const long off = cbase + (long)row * ldc + coln;
                float v[4];
#pragma unroll
                for (int r = 0; r < 4; r++) v[r] = acc[i][j][r];
                if constexpr (EPI == EPI_BN) {
                    float rs[4]; ld4bf(p.res + (long)row * ldc + coln, rs);
#pragma unroll
                    for (int r = 0; r < 4; r++) v[r] = sc4[r] * v[r] + sh4[r] + rs[r];
                } else {
#pragma unroll
                    for (int r = 0; r < 4; r++) v[r] = sc4[r] * v[r] + sh4[r];
                }
                if constexpr (DYNOUT) {
                    if (isf32) *(f32x4*)((float*)p.Cv + off) = (f32x4){v[0], v[1], v[2], v[3]};
                    else       *(u32x2*)((ushort_t*)p.Cv + off) = pk4bf(v);
                } else {
                    *(u32x2*)((ushort_t*)p.Cv + off) = pk4bf(v);
                }
            }
        }
    } else {
        const bool doC = (n0 < p.cnmax);
#pragma unroll
        for (int j = 0; j < 2; j++) {
            const int col = n0 + wc * 32 + j * 16 + lr;
            float bs = 0.f;
            if constexpr (EPI == EPI_BIAS) bs = bf2f(p.bias[col]);
#pragma unroll
            for (int i = 0; i < 4; i++) {
                const int rowbase = m0 + i * 16 + q * 4;
                ushort_t tmp[4];
#pragma unroll
                for (int r = 0; r < 4; r++) {
                    const int row = rowbase + r;
                    float v = acc[i][j][r];
                    if constexpr (EPI == EPI_BIAS) v += bs;
                    const long off = cbase + (long)row * ldc + col;
                    const ushort_t us2 = f2bf(v);
                    tmp[r] = us2;
                    if (doC) ((ushort_t*)p.Cv)[off] = us2;
                }
                if constexpr (DUALT) {
                    u32x2 pk;
                    pk[0] = (uint32)tmp[0] | ((uint32)tmp[1] << 16);
                    pk[1] = (uint32)tmp[2] | ((uint32)tmp[3] << 16);
                    *(u32x2*)(p.CT + (long)col * p.ldT + rowbase) = pk;
                }
            }
        }
    }
}

extern "C" void kernel_launch(void* const* d_in, const int* in_sizes, int n_in,
                              void* d_out, int out_size, void* d_ws, size_t ws_size,
                              hipStream_t stream)
{
    int* flag = (int*)d_ws;
    ushort_t* base = (ushort_t*)((char*)d_ws + 512);
    long o = 0;
    ushort_t* detect_c = base + o; o += 16777216;   // [32768][512]
    ushort_t* aim_c    = base + o; o += 4194304;    // [8192][512]
    ushort_t* WpgT = base + o; o += 262144;         // [512][512] = [WpT; WgT]
    ushort_t* WtgT = base + o; o += 262144;         // [512][512] = [WtT; WgT]
    ushort_t* WwT  = base + o; o += 131072;         // [512][256]
    ushort_t* WqT  = base + o; o += 131072;
    ushort_t* bpg_c  = base + o; o += 512;
    ushort_t* btg_c  = base + o; o += 512;
    ushort_t* bw_c   = base + o; o += 512;
    ushort_t* gw_c   = base + o; o += 512;
    ushort_t* betw_c = base + o; o += 512;
    ushort_t* mw_c   = base + o; o += 512;
    ushort_t* vw_c   = base + o; o += 512;
    ushort_t* bq_c   = base + o; o += 512;
    ushort_t* gq_c   = base + o; o += 512;
    ushort_t* betq_c = base + o; o += 512;
    ushort_t* mq_c   = base + o; o += 512;
    ushort_t* vq_c   = base + o; o += 512;
    ushort_t* phi    = base + o; o += 8388608;      // [32768][256]
    ushort_t* PT     = base + o; o += 16777216;     // [512][32768]: phiT + d_xT
    ushort_t* theta  = base + o; o += 2097152;      // [8192][256]
    ushort_t* TT     = base + o; o += 4194304;      // [512][8192]: thetaT + a_xT
    ushort_t* G1     = base + o; o += 524288;       // [8][256][256] bf16 (plain)
    ushort_t* G2     = base + o; o += 524288;
    ushort_t* M1T    = base + o; o += 1048576;      // [8][512][256] = (G1/4096 · Ww)^T
    ushort_t* M2T    = base + o; o += 1048576;      // [8][512][256] = (G2/1024 · Wq)^T
    ushort_t* U      = base + o; o += 16777216;     // P1,P2 bf16 (128 slices each)
    ushort_t* P1 = U;                               // [128][65536] bf16
    ushort_t* P2 = P1 + 8388608;
    ushort_t* phiT = PT;
    ushort_t* d_xT = PT + 8388608;
    ushort_t* thetaT = TT;
    ushort_t* a_xT = TT + 2097152;

    VecArgs va;
    const int vidx[14] = {7, 3, 5, 3, 9, 10, 11, 12, 13, 15, 16, 17, 18, 19};
    ushort_t* vdst[14] = {bpg_c, bpg_c + 256, btg_c, btg_c + 256,
                          bw_c, gw_c, betw_c, mw_c, vw_c,
                          bq_c, gq_c, betq_c, mq_c, vq_c};
    const int vn[14] = {256, 256, 256, 256, 512, 512, 512, 512, 512, 512, 512, 512, 512, 512};
    for (int i = 0; i < 14; i++) { va.s[i] = d_in[vidx[i]]; va.d[i] = vdst[i]; va.n[i] = vn[i]; }

    WtArgs wa;
    wa.s[0] = d_in[6];  wa.d[0] = WpgT;              wa.R[0] = 512; wa.C[0] = 256;
    wa.s[1] = d_in[2];  wa.d[1] = WpgT + 256 * 512;  wa.R[1] = 512; wa.C[1] = 256;
    wa.s[2] = d_in[4];  wa.d[2] = WtgT;              wa.R[2] = 512; wa.C[2] = 256;
    wa.s[3] = d_in[2];  wa.d[3] = WtgT + 256 * 512;  wa.R[3] = 512; wa.C[3] = 256;
    wa.s[4] = d_in[8];  wa.d[4] = WwT;               wa.R[4] = 256; wa.C[4] = 512;
    wa.s[5] = d_in[14]; wa.d[5] = WqT;               wa.R[5] = 256; wa.C[5] = 512;

    // ONE canon launch: activations + weights-T + small vectors + flag publish
    canon_all<<<4609, 256, 0, stream>>>(d_in[0], detect_c, d_in[1], aim_c, wa, va, flag);

    const dim3 blk(256);
    const ushort_t* np = nullptr;
    ushort_t* npm = nullptr;

    // merged convs (64-row tiles, 2560 blocks): phi/theta + phiT/d_xT + thetaT/a_xT
    {
        GP2 g;
        g.g[0] = GP{detect_c, WpgT, phi, PT, bpg_c, np, np, np, np, np,
                    0, 0, 0, 0, 512, 512, 512, 256, 256, 32768, 30, ALLM, 1.f};
        g.g[1] = GP{aim_c, WtgT, theta, TT, btg_c, np, np, np, np, np,
                    0, 0, 0, 0, 512, 512, 512, 256, 256, 8192, 30, ALLM, 1.f};
        gemm_nt64<EPI_BIAS, false, true, false><<<dim3(4, 640, 1), blk, 0, stream>>>(
            g, 512, flag);
    }

    // merged split-K partials on 64-row tiles (2048 blocks, 6/CU resident):
    // by = slice*4 + mtile; bz = by>>2 selects K-slice (sA/sB=k-offset, sC=P-slice).
    // EPI_SCALE alpha=1 -> plain bf16 partial store via SWAP epilogue.
    {
        GP2 g;
        g.g[0] = GP{phiT, d_xT, P1, npm, np, np, np, np, np, np,
                    0, 256, 256, 65536, 256, 32768, 32768, 256, BIGN, 0, 2, 3, 1.f};
        g.g[1] = GP{thetaT, a_xT, P2, npm, np, np, np, np, np, np,
                    0, 64, 64, 65536, 64, 8192, 8192, 256, BIGN, 0, 2, 3, 1.f};
        gemm_nt64<EPI_SCALE, false, false, true><<<dim3(2, 1024, 1), blk, 0, stream>>>(
            g, 512, flag);
    }

    // reduce 16 bf16 partial slices -> plain bf16 G (scale folded): 512 blocks
    reduce_g_kernel<<<512, blk, 0, stream>>>(P1, P2, G1, G2);

    // tiny per-batch M = G · W^T, stored transposed (CT path): 128 blocks
    {
        GP2 g;
        g.g[0] = GP{G1, WwT, npm, M1T, np, np, np, np, np, np,
                    0, 65536, 0, 131072, 256, 256, 256, 512, 0, 256, 30, ALLM, 1.f};
        g.g[1] = GP{G2, WqT, npm, M2T, np, np, np, np, np, np,
                    0, 65536, 0, 131072, 256, 256, 256, 512, 0, 256, 30, ALLM, 1.f};
        gemm_nt<EPI_SCALE, false, true, false><<<dim3(4, 2, 16), blk, 0, stream>>>(
            g, BIGN, 8, flag);
    }

    // outputs (64-row tiles, 2560 blocks): out1 = BN(phi·M2[b]+bq)+detect ;
    // out0 = BN(theta·M1[b]+bw)+aim. bz = batch selects M panel (sB=131072).
    {
        GP2 g;
        g.g[0] = GP{phi, M2T, d_out, npm, bq_c, gq_c, betq_c, mq_c, vq_c, detect_c,
                    8192L * 512, 0, 131072, 0, 256, 256, 256, 512, BIGN, 0, 6, ALLM, 1.f};
        g.g[1] = GP{theta, M1T, d_out, npm, bw_c, gw_c, betw_c, mw_c, vw_c, aim_c,
                    0, 0, 131072, 0, 256, 256, 256, 512, BIGN, 0, 4, ALLM, 1.f};
        gemm_nt64<EPI_BN, true, false, true><<<dim3(4, 640, 1), blk, 0, stream>>>(
            g, 512, flag);
    }
}

// Round 18
// 320.558 us; speedup vs baseline: 1.0163x; 1.0163x over previous
//
#include <hip/hip_runtime.h>

typedef unsigned short ushort_t;
typedef unsigned int uint32;
typedef __bf16 bf16x8 __attribute__((ext_vector_type(8)));
typedef float f32x4 __attribute__((ext_vector_type(4)));
typedef uint32 u32x4 __attribute__((ext_vector_type(4)));
typedef uint32 u32x2 __attribute__((ext_vector_type(2)));

typedef __attribute__((address_space(3))) uint32 as3_u32;
typedef const __attribute__((address_space(1))) uint32 as1_u32c;

// async global->LDS, 16B per lane; LDS dest = wave-uniform base + lane*16
__device__ __forceinline__ void gl_lds16(const ushort_t* g, ushort_t* l) {
    __builtin_amdgcn_global_load_lds((as1_u32c*)g, (as3_u32*)l, 16, 0, 0);
}

__device__ __forceinline__ float bf2f(ushort_t u) {
    uint32 x = ((uint32)u) << 16;
    return __builtin_bit_cast(float, x);
}
__device__ __forceinline__ ushort_t f2bf(float f) {
    uint32 x = __builtin_bit_cast(uint32, f);
    x += 0x7fffu + ((x >> 16) & 1u);   // RNE
    return (ushort_t)(x >> 16);
}
__device__ __forceinline__ void ld4bf(const ushort_t* p, float* f) {
    const u32x2 w = *(const u32x2*)p;
    f[0] = bf2f((ushort_t)(w[0] & 0xffffu)); f[1] = bf2f((ushort_t)(w[0] >> 16));
    f[2] = bf2f((ushort_t)(w[1] & 0xffffu)); f[3] = bf2f((ushort_t)(w[1] >> 16));
}
__device__ __forceinline__ u32x2 pk4bf(const float* v) {
    u32x2 pk;
    pk[0] = (uint32)f2bf(v[0]) | ((uint32)f2bf(v[1]) << 16);
    pk[1] = (uint32)f2bf(v[2]) | ((uint32)f2bf(v[3]) << 16);
    return pk;
}

// per-block dtype sniff: read first 1KB of detect, count non-f32-like exponents
__device__ __forceinline__ bool sniff(const void* in0) {
    const uint32* s = (const uint32*)in0;
    const int lane = threadIdx.x & 63;
    int wd = 0;
    for (int c = 0; c < 4; c++) {
        const uint32 w = s[lane * 4 + c];
        const uint32 e = (w >> 7) & 0xFFu;
        wd += (e < 64u) || (e >= 192u);
    }
    for (int off = 32; off; off >>= 1) wd += __shfl_down(wd, off);
    return __shfl(wd, 0) > 32;
}

// ALL canon work in ONE launch (4609 blocks), dtype sniffed per-block
struct VecArgs { const void* s[14]; ushort_t* d[14]; int n[14]; };
struct WtArgs { const void* s[6]; ushort_t* d[6]; int R[6]; int C[6]; };
__global__ void canon_all(const void* __restrict__ dsrc, ushort_t* __restrict__ ddst,
                          const void* __restrict__ asrc, ushort_t* __restrict__ adst,
                          WtArgs wa, VecArgs va, int* __restrict__ flag) {
    const bool isf32 = sniff(dsrc);
    const int b = blockIdx.x;
    if (b < 3072) {
        const void* src; ushort_t* dst; long n; int b0, nb;
        if (b < 2560) { src = dsrc; dst = ddst; n = 16777216; b0 = b; nb = 2560; }
        else          { src = asrc; dst = adst; n = 4194304;  b0 = b - 2560; nb = 512; }
        long i = ((long)b0 * 256 + threadIdx.x) * 16;
        const long stride = (long)nb * 256 * 16;
        if (isf32) {
            const float* s = (const float*)src;
            for (; i < n; i += stride) {
                const f32x4 a0 = *(const f32x4*)(s + i);
                const f32x4 a1 = *(const f32x4*)(s + i + 4);
                const f32x4 a2 = *(const f32x4*)(s + i + 8);
                const f32x4 a3 = *(const f32x4*)(s + i + 12);
                u32x4 o0, o1;
                o0[0] = (uint32)f2bf(a0[0]) | ((uint32)f2bf(a0[1]) << 16);
                o0[1] = (uint32)f2bf(a0[2]) | ((uint32)f2bf(a0[3]) << 16);
                o0[2] = (uint32)f2bf(a1[0]) | ((uint32)f2bf(a1[1]) << 16);
                o0[3] = (uint32)f2bf(a1[2]) | ((uint32)f2bf(a1[3]) << 16);
                o1[0] = (uint32)f2bf(a2[0]) | ((uint32)f2bf(a2[1]) << 16);
                o1[1] = (uint32)f2bf(a2[2]) | ((uint32)f2bf(a2[3]) << 16);
                o1[2] = (uint32)f2bf(a3[0]) | ((uint32)f2bf(a3[1]) << 16);
                o1[3] = (uint32)f2bf(a3[2]) | ((uint32)f2bf(a3[3]) << 16);
                *(u32x4*)(dst + i) = o0;
                *(u32x4*)(dst + i + 8) = o1;
            }
        } else {
            const ushort_t* s = (const ushort_t*)src;
            for (; i < n; i += stride) {
                const u32x4 v0 = *(const u32x4*)(s + i);
                const u32x4 v1 = *(const u32x4*)(s + i + 8);
                *(u32x4*)(dst + i) = v0;
                *(u32x4*)(dst + i + 8) = v1;
            }
        }
    } else if (b < 4608) {
        const int local = b - 3072;
        const int wsel = local >> 8;
        const int rem = local & 255;
        const int tr = rem >> 4, tc = rem & 15;
        const int R = wa.R[wsel], C = wa.C[wsel];
        if (tc * 32 >= C || tr * 32 >= R) return;
        __shared__ float s[32][33];
        const int t = threadIdx.x;
        const int r = t >> 3, c4 = (t & 7) * 4;
        const long sbase = (long)(tr * 32 + r) * C + tc * 32 + c4;
        if (isf32) {
            const float* S = (const float*)wa.s[wsel];
            const f32x4 v = *(const f32x4*)(S + sbase);
            for (int u = 0; u < 4; u++) s[r][c4 + u] = v[u];
        } else {
            const ushort_t* S = (const ushort_t*)wa.s[wsel];
            for (int u = 0; u < 4; u++) s[r][c4 + u] = bf2f(S[sbase + u]);
        }
        __syncthreads();
        float tv[4];
        for (int u = 0; u < 4; u++) tv[u] = s[c4 + u][r];
        *(u32x2*)(wa.d[wsel] + (long)(tc * 32 + r) * R + tr * 32 + c4) = pk4bf(tv);
    } else {
        if (threadIdx.x == 0) *flag = isf32 ? 1 : 0;
        const int t = threadIdx.x;
        for (int seg = 0; seg < 14; seg++) {
            const int n = va.n[seg];
            if (isf32) {
                const float* s = (const float*)va.s[seg];
                for (int i = t; i < n; i += 256) va.d[seg][i] = f2bf(s[i]);
            } else {
                const ushort_t* s = (const ushort_t*)va.s[seg];
                for (int i = t; i < n; i += 256) va.d[seg][i] = s[i];
            }
        }
    }
}

// reduce 16 bf16 split-K partial slices -> plain bf16 G (scale folded in).
// 512 blocks, 8 elems/thread: zz = b>>5 selects (matrix,batch).
__global__ void reduce_g_kernel(const ushort_t* __restrict__ P1,
                                const ushort_t* __restrict__ P2,
                                ushort_t* __restrict__ G1, ushort_t* __restrict__ G2) {
    const int bxv = blockIdx.x;
    const int zz = bxv >> 5;                    // 0..15
    const ushort_t* P = (zz < 8) ? P1 : P2;
    ushort_t* G    = (zz < 8) ? G1 : G2;
    const float alpha = (zz < 8) ? (1.f / 4096.f) : (1.f / 1024.f);
    const int b = zz & 7;
    const long off = ((long)(bxv & 31) * 256 + threadIdx.x) * 8;
    const ushort_t* base = P + (long)b * 16 * 65536 + off;
    float acc[8] = {0, 0, 0, 0, 0, 0, 0, 0};
    for (int kc = 0; kc < 16; kc++) {
        const ushort_t* s = base + (long)kc * 65536;
        float f0[4], f1[4];
        ld4bf(s, f0); ld4bf(s + 4, f1);
#pragma unroll
        for (int u = 0; u < 4; u++) { acc[u] += f0[u]; acc[4 + u] += f1[u]; }
    }
    float v0[4], v1[4];
#pragma unroll
    for (int u = 0; u < 4; u++) { v0[u] = acc[u] * alpha; v1[u] = acc[4 + u] * alpha; }
    u32x4 o;
    const u32x2 p0 = pk4bf(v0), p1 = pk4bf(v1);
    o[0] = p0[0]; o[1] = p0[1]; o[2] = p1[0]; o[3] = p1[1];
    *(u32x4*)(G + (long)b * 65536 + off) = o;
}

#define BM 128
#define BN 128
#define BK 32
#define LDSH (BM * BK)
#define NBUF 3
#define BIGN (1 << 30)

enum { EPI_BIAS = 0, EPI_BIASR = 1, EPI_SCALE = 2, EPI_BN = 3, EPI_PART = 4 };

struct GP {
    const ushort_t* A; const ushort_t* B; void* Cv; ushort_t* CT;
    const ushort_t* bias; const ushort_t* gamma; const ushort_t* beta;
    const ushort_t* mean; const ushort_t* var; const ushort_t* res;
    long coff, sA, sB, sC;
    int K, lda, ldb, ldc, cnmax, ldT, bshift;
    float alpha;
};
struct GP2 { GP g[2]; };

// NT GEMM 128x128 (r6-proven): depth-3 rotating LDS pipeline, 1 barrier/K-step.
// EPI_PART stores bf16 partials (u32x2), halving split-K round-trip traffic.
template <int EPI, bool DYNOUT, bool DUALT, bool SWAP>
__global__ __launch_bounds__(256) void gemm_nt(GP2 ga, int ysplit, int zsplit,
                                               const int* __restrict__ flag)
{
    __shared__ __align__(16) ushort_t As[NBUF * LDSH];
    __shared__ __align__(16) ushort_t Bs[NBUF * LDSH];

    const bool isf32 = DYNOUT ? (*flag != 0) : false;

    const uint32 gx = gridDim.x, gy = gridDim.y;
    const uint32 nwg = gx * gy * gridDim.z;
    const uint32 lid = blockIdx.x + gx * (blockIdx.y + gy * blockIdx.z);
    const uint32 swz = (lid & 7u) * (nwg >> 3) + (lid >> 3);
    const uint32 bx = swz % gx, t1 = swz / gx;
    int by = (int)(t1 % gy), bz = (int)(t1 / gy);

    int sel = 0;
    if (by >= ysplit) { by -= ysplit; sel = 1; }
    if (bz >= zsplit) { bz -= zsplit; sel = 1; }
    const GP& p = ga.g[sel];

    const ushort_t* A = p.A + (long)bz * p.sA;
    const ushort_t* B = p.B + ((long)bz + (long)(by >> p.bshift)) * p.sB;
    const long cbase = p.coff + (long)bz * p.sC;
    const int lda = p.lda, ldb = p.ldb, ldc = p.ldc, K = p.K;

    const int tid  = threadIdx.x;
    const int lane = tid & 63;
    const int w    = tid >> 6;
    const int wr   = w >> 1, wc = w & 1;
    const int lr   = lane & 15, q = lane >> 4;

    const int m0 = by * BM;
    const int n0 = bx * BN;

    const int lrow = lane >> 2, lu = lane & 3;
    const int us = (lu ^ ((lrow >> 1) & 3)) * 8;
    const int ra0 = w * 32 + lrow, ra1 = w * 32 + 16 + lrow;
    const ushort_t* Ar0 = A + (long)(m0 + ra0) * lda + us;
    const ushort_t* Ar1 = A + (long)(m0 + ra1) * lda + us;
    const ushort_t* Br0 = B + (long)(n0 + ra0) * ldb + us;
    const ushort_t* Br1 = B + (long)(n0 + ra1) * ldb + us;
    ushort_t* sA0 = &As[(w * 2 + 0) * 512];
    ushort_t* sA1 = &As[(w * 2 + 1) * 512];
    ushort_t* sB0 = &Bs[(w * 2 + 0) * 512];
    ushort_t* sB1 = &Bs[(w * 2 + 1) * 512];

    const int swq = (q ^ ((lr >> 1) & 3)) * 8;

    f32x4 acc[4][4];
#pragma unroll
    for (int i = 0; i < 4; i++)
#pragma unroll
        for (int j = 0; j < 4; j++) acc[i][j] = (f32x4){0.f, 0.f, 0.f, 0.f};

    const int nt = K / BK;
    {
        gl_lds16(Ar0, sA0); gl_lds16(Ar1, sA1);
        gl_lds16(Br0, sB0); gl_lds16(Br1, sB1);
        if (nt > 1) {
            gl_lds16(Ar0 + BK, sA0 + LDSH); gl_lds16(Ar1 + BK, sA1 + LDSH);
            gl_lds16(Br0 + BK, sB0 + LDSH); gl_lds16(Br1 + BK, sB1 + LDSH);
        }
    }

    int c0 = 0, c2 = 2;
    for (int t = 0; t < nt; ++t) {
        if (t + 1 < nt) asm volatile("s_waitcnt vmcnt(4)" ::: "memory");
        else            asm volatile("s_waitcnt vmcnt(0)" ::: "memory");
        __builtin_amdgcn_s_barrier();
        __builtin_amdgcn_sched_barrier(0);

        if (t + 2 < nt) {
            const int nb = c2 * LDSH;
            const int kn = (t + 2) * BK;
            gl_lds16(Ar0 + kn, sA0 + nb); gl_lds16(Ar1 + kn, sA1 + nb);
            gl_lds16(Br0 + kn, sB0 + nb); gl_lds16(Br1 + kn, sB1 + nb);
        }
        __builtin_amdgcn_sched_barrier(0);

        const ushort_t* Ab = As + c0 * LDSH;
        const ushort_t* Bb = Bs + c0 * LDSH;
        bf16x8 af[4], bfr[4];
#pragma unroll
        for (int i = 0; i < 4; i++)
            af[i] = __builtin_bit_cast(bf16x8,
                *(const u32x4*)(&Ab[(wr * 64 + i * 16 + lr) * BK + swq]));
#pragma unroll
        for (int j = 0; j < 4; j++)
            bfr[j] = __builtin_bit_cast(bf16x8,
                *(const u32x4*)(&Bb[(wc * 64 + j * 16 + lr) * BK + swq]));
#pragma unroll
        for (int i = 0; i < 4; i++)
#pragma unroll
            for (int j = 0; j < 4; j++) {
                if constexpr (SWAP)
                    acc[i][j] = __builtin_amdgcn_mfma_f32_16x16x32_bf16(bfr[j], af[i], acc[i][j], 0, 0, 0);
                else
                    acc[i][j] = __builtin_amdgcn_mfma_f32_16x16x32_bf16(af[i], bfr[j], acc[i][j], 0, 0, 0);
            }
        __builtin_amdgcn_sched_barrier(0);

        c0 = (c0 + 1 == NBUF) ? 0 : c0 + 1;
        c2 = (c2 + 1 == NBUF) ? 0 : c2 + 1;
    }

    if constexpr (SWAP) {
#pragma unroll
        for (int j = 0; j < 4; j++) {
            const int coln = n0 + wc * 64 + j * 16 + q * 4;
#pragma unroll
            for (int i = 0; i < 4; i++) {
                const int row = m0 + wr * 64 + i * 16 + lr;
                const long off = cbase + (long)row * ldc + coln;
                float v[4];
#pragma unroll
                for (int r = 0; r < 4; r++) v[r] = acc[i][j][r];
                if constexpr (EPI == EPI_PART) {
                    *(u32x2*)((ushort_t*)p.Cv + off) = pk4bf(v);   // bf16 partials
                } else if constexpr (DYNOUT) {
                    if (isf32) *(f32x4*)((float*)p.Cv + off) = (f32x4){v[0], v[1], v[2], v[3]};
                    else       *(u32x2*)((ushort_t*)p.Cv + off) = pk4bf(v);
                } else {
                    *(u32x2*)((ushort_t*)p.Cv + off) = pk4bf(v);
                }
            }
        }
    } else {
        const bool doC = (n0 < p.cnmax);
#pragma unroll
        for (int j = 0; j < 4; j++) {
            const int col = n0 + wc * 64 + j * 16 + lr;
            float bs = 0.f;
            if constexpr (EPI == EPI_BIAS) bs = bf2f(p.bias[col]);
#pragma unroll
            for (int i = 0; i < 4; i++) {
                const int rowbase = m0 + wr * 64 + i * 16 + q * 4;
                ushort_t tmp[4];
#pragma unroll
                for (int r = 0; r < 4; r++) {
                    const int row = rowbase + r;
                    float v = acc[i][j][r];
                    if constexpr (EPI == EPI_BIAS) v += bs;
                    else if constexpr (EPI == EPI_BIASR) v += bf2f(p.bias[row]);
                    else if constexpr (EPI == EPI_SCALE) v *= p.alpha;
                    const long off = cbase + (long)row * ldc + col;
                    const ushort_t us2 = f2bf(v);
                    tmp[r] = us2;
                    if constexpr (EPI == EPI_PART) {
                        ((ushort_t*)p.Cv)[off] = us2;
                    } else {
                        if (doC) ((ushort_t*)p.Cv)[off] = us2;
                    }
                }
                if constexpr (DUALT) {
                    u32x2 pk;
                    pk[0] = (uint32)tmp[0] | ((uint32)tmp[1] << 16);
                    pk[1] = (uint32)tmp[2] | ((uint32)tmp[3] << 16);
                    *(u32x2*)(p.CT + (long)bz * p.sC + (long)col * p.ldT + rowbase) = pk;
                }
            }
        }
    }
}

// ---- NT GEMM 64x128: half-M tile, 2x blocks, 24KB LDS -> 6 blocks/CU. ----
// 4 waves, each owns a 64x32 output strip (acc 4x2). Staging: 3 gl_lds/wave/tile,
// NBUF=2, counted vmcnt(3). Wave segs: A at w*512, B at (w*2+k)*512.
// Best for conv/out (small L2-hot B panels); NOT for partials (large B).
#define LDSA64 (64 * 32)
#define LDSB64 (128 * 32)
template <int EPI, bool DYNOUT, bool DUALT, bool SWAP>
__global__ __launch_bounds__(256) void gemm_nt64(GP2 ga, int ysplit,
                                                 const int* __restrict__ flag)
{
    __shared__ __align__(16) ushort_t As[2 * LDSA64];
    __shared__ __align__(16) ushort_t Bs[2 * LDSB64];

    const bool isf32 = DYNOUT ? (*flag != 0) : false;

    const uint32 gx = gridDim.x, gy = gridDim.y;
    const uint32 nwg = gx * gy;
    const uint32 lid = blockIdx.x + gx * blockIdx.y;
    const uint32 swz = (lid & 7u) * (nwg >> 3) + (lid >> 3);
    const uint32 bx = swz % gx;
    int by = (int)(swz / gx);

    int sel = 0;
    if (by >= ysplit) { by -= ysplit; sel = 1; }
    const GP& p = ga.g[sel];

    const ushort_t* A = p.A;
    const ushort_t* B = p.B + (long)(by >> p.bshift) * p.sB;
    const long cbase = p.coff;
    const int lda = p.lda, ldb = p.ldb, ldc = p.ldc, K = p.K;

    const int tid  = threadIdx.x;
    const int lane = tid & 63;
    const int w    = tid >> 6;
    const int wc   = w;                      // 4 waves across N (32 cols each)
    const int lr   = lane & 15, q = lane >> 4;

    const int m0 = by * 64;
    const int n0 = bx * BN;

    const int lrow = lane >> 2, lu = lane & 3;
    const int us = (lu ^ ((lrow >> 1) & 3)) * 8;          // source-side swizzle
    const ushort_t* ArS = A + (long)(m0 + w * 16 + lrow) * lda + us;
    const ushort_t* Br0 = B + (long)(n0 + w * 32 + lrow) * ldb + us;
    const ushort_t* Br1 = B + (long)(n0 + w * 32 + 16 + lrow) * ldb + us;
    ushort_t* sAw = &As[w * 512];
    ushort_t* sB0 = &Bs[(w * 2 + 0) * 512];
    ushort_t* sB1 = &Bs[(w * 2 + 1) * 512];

    const int swq = (q ^ ((lr >> 1) & 3)) * 8;            // read-side swizzle

    f32x4 acc[4][2];
#pragma unroll
    for (int i = 0; i < 4; i++)
#pragma unroll
        for (int j = 0; j < 2; j++) acc[i][j] = (f32x4){0.f, 0.f, 0.f, 0.f};

    const int nt = K / BK;
    gl_lds16(ArS, sAw);
    gl_lds16(Br0, sB0);
    gl_lds16(Br1, sB1);

    for (int t = 0; t < nt; ++t) {
        const int cur = t & 1;
        if (t + 1 < nt) {
            const int kn = (t + 1) * BK;
            const int nbA = (cur ^ 1) * LDSA64, nbB = (cur ^ 1) * LDSB64;
            gl_lds16(ArS + kn, sAw + nbA);
            gl_lds16(Br0 + kn, sB0 + nbB);
            gl_lds16(Br1 + kn, sB1 + nbB);
            asm volatile("s_waitcnt vmcnt(3)" ::: "memory");
        } else {
            asm volatile("s_waitcnt vmcnt(0)" ::: "memory");
        }
        __builtin_amdgcn_s_barrier();
        __builtin_amdgcn_sched_barrier(0);

        const ushort_t* Ab = As + cur * LDSA64;
        const ushort_t* Bb = Bs + cur * LDSB64;
        bf16x8 af[4], bfr[2];
#pragma unroll
        for (int i = 0; i < 4; i++)
            af[i] = __builtin_bit_cast(bf16x8,
                *(const u32x4*)(&Ab[(i * 16 + lr) * BK + swq]));
#pragma unroll
        for (int j = 0; j < 2; j++)
            bfr[j] = __builtin_bit_cast(bf16x8,
                *(const u32x4*)(&Bb[(wc * 32 + j * 16 + lr) * BK + swq]));
#pragma unroll
        for (int i = 0; i < 4; i++)
#pragma unroll
            for (int j = 0; j < 2; j++) {
                if constexpr (SWAP)
                    acc[i][j] = __builtin_amdgcn_mfma_f32_16x16x32_bf16(bfr[j], af[i], acc[i][j], 0, 0, 0);
                else
                    acc[i][j] = __builtin_amdgcn_mfma_f32_16x16x32_bf16(af[i], bfr[j], acc[i][j], 0, 0, 0);
            }
        __builtin_amdgcn_sched_barrier(0);
        asm volatile("" ::: "memory");
        __builtin_amdgcn_s_barrier();
    }

    if constexpr (SWAP) {
#pragma unroll
        for (int j = 0; j < 2; j++) {
            const int coln = n0 + wc * 32 + j * 16 + q * 4;
            float sc4[4], sh4[4];
            if constexpr (EPI == EPI_BN) {
                float bb[4], g[4], bt[4], mn[4], vr[4];
                ld4bf(p.bias + coln, bb); ld4bf(p.gamma + coln, g); ld4bf(p.beta + coln, bt);
                ld4bf(p.mean + coln, mn); ld4bf(p.var + coln, vr);
#pragma unroll
                for (int r = 0; r < 4; r++) {
                    const float s = g[r] * rsqrtf(vr[r] + 1e-3f);
                    sc4[r] = s;
                    sh4[r] = s * bb[r] + bt[r] - s * mn[r];
                }
            } else if constexpr (EPI == EPI_BIAS) {
                float bb[4]; ld4bf(p.bias + coln, bb);
#pragma unroll
                for (int r = 0; r < 4; r++) { sc4[r] = 1.f; sh4[r] = bb[r]; }
            } else {
#pragma unroll
                for (int r = 0; r < 4; r++) { sc4[r] = p.alpha; sh4[r] = 0.f; }
            }
#pragma unroll
            for (int i = 0; i < 4; i++) {
                const int row = m0 + i * 16 + lr;
                const long off = cbase + (long)row * ldc + coln;
                float v[4];
#pragma unroll
                for (int r = 0; r < 4; r++) v[r] = acc[i][j][r];
                if constexpr (EPI == EPI_BN) {
                    float rs[4]; ld4bf(p.res + (long)row * ldc + coln, rs);
#pragma unroll
                    for (int r = 0; r < 4; r++) v[r] = sc4[r] * v[r] + sh4[r] + rs[r];
                } else {
#pragma unroll
                    for (int r = 0; r < 4; r++) v[r] = sc4[r] * v[r] + sh4[r];
                }
                if constexpr (DYNOUT) {
                    if (isf32) *(f32x4*)((float*)p.Cv + off) = (f32x4){v[0], v[1], v[2], v[3]};
                    else       *(u32x2*)((ushort_t*)p.Cv + off) = pk4bf(v);
                } else {
                    *(u32x2*)((ushort_t*)p.Cv + off) = pk4bf(v);
                }
            }
        }
    } else {
        const bool doC = (n0 < p.cnmax);
#pragma unroll
        for (int j = 0; j < 2; j++) {
            const int col = n0 + wc * 32 + j * 16 + lr;
            float bs = 0.f;
            if constexpr (EPI == EPI_BIAS) bs = bf2f(p.bias[col]);
#pragma unroll
            for (int i = 0; i < 4; i++) {
                const int rowbase = m0 + i * 16 + q * 4;
                ushort_t tmp[4];
#pragma unroll
                for (int r = 0; r < 4; r++) {
                    const int row = rowbase + r;
                    float v = acc[i][j][r];
                    if constexpr (EPI == EPI_BIAS) v += bs;
                    const long off = cbase + (long)row * ldc + col;
                    const ushort_t us2 = f2bf(v);
                    tmp[r] = us2;
                    if (doC) ((ushort_t*)p.Cv)[off] = us2;
                }
                if constexpr (DUALT) {
                    u32x2 pk;
                    pk[0] = (uint32)tmp[0] | ((uint32)tmp[1] << 16);
                    pk[1] = (uint32)tmp[2] | ((uint32)tmp[3] << 16);
                    *(u32x2*)(p.CT + (long)col * p.ldT + rowbase) = pk;
                }
            }
        }
    }
}

extern "C" void kernel_launch(void* const* d_in, const int* in_sizes, int n_in,
                              void* d_out, int out_size, void* d_ws, size_t ws_size,
                              hipStream_t stream)
{
    int* flag = (int*)d_ws;
    ushort_t* base = (ushort_t*)((char*)d_ws + 512);
    long o = 0;
    ushort_t* detect_c = base + o; o += 16777216;   // [32768][512]
    ushort_t* aim_c    = base + o; o += 4194304;    // [8192][512]
    ushort_t* WpgT = base + o; o += 262144;         // [512][512] = [WpT; WgT]
    ushort_t* WtgT = base + o; o += 262144;         // [512][512] = [WtT; WgT]
    ushort_t* WwT  = base + o; o += 131072;         // [512][256]
    ushort_t* WqT  = base + o; o += 131072;
    ushort_t* bpg_c  = base + o; o += 512;
    ushort_t* btg_c  = base + o; o += 512;
    ushort_t* bw_c   = base + o; o += 512;
    ushort_t* gw_c   = base + o; o += 512;
    ushort_t* betw_c = base + o; o += 512;
    ushort_t* mw_c   = base + o; o += 512;
    ushort_t* vw_c   = base + o; o += 512;
    ushort_t* bq_c   = base + o; o += 512;
    ushort_t* gq_c   = base + o; o += 512;
    ushort_t* betq_c = base + o; o += 512;
    ushort_t* mq_c   = base + o; o += 512;
    ushort_t* vq_c   = base + o; o += 512;
    ushort_t* phi    = base + o; o += 8388608;      // [32768][256]
    ushort_t* PT     = base + o; o += 16777216;     // [512][32768]: phiT + d_xT
    ushort_t* theta  = base + o; o += 2097152;      // [8192][256]
    ushort_t* TT     = base + o; o += 4194304;      // [512][8192]: thetaT + a_xT
    ushort_t* G1     = base + o; o += 524288;       // [8][256][256] bf16 (plain)
    ushort_t* G2     = base + o; o += 524288;
    ushort_t* M1T    = base + o; o += 1048576;      // [8][512][256] = (G1/4096 · Ww)^T
    ushort_t* M2T    = base + o; o += 1048576;      // [8][512][256] = (G2/1024 · Wq)^T
    ushort_t* U      = base + o; o += 16777216;     // P1,P2 bf16 (128 slices each)
    ushort_t* P1 = U;                               // [128][65536] bf16
    ushort_t* P2 = P1 + 8388608;
    ushort_t* phiT = PT;
    ushort_t* d_xT = PT + 8388608;
    ushort_t* thetaT = TT;
    ushort_t* a_xT = TT + 2097152;

    VecArgs va;
    const int vidx[14] = {7, 3, 5, 3, 9, 10, 11, 12, 13, 15, 16, 17, 18, 19};
    ushort_t* vdst[14] = {bpg_c, bpg_c + 256, btg_c, btg_c + 256,
                          bw_c, gw_c, betw_c, mw_c, vw_c,
                          bq_c, gq_c, betq_c, mq_c, vq_c};
    const int vn[14] = {256, 256, 256, 256, 512, 512, 512, 512, 512, 512, 512, 512, 512, 512};
    for (int i = 0; i < 14; i++) { va.s[i] = d_in[vidx[i]]; va.d[i] = vdst[i]; va.n[i] = vn[i]; }

    WtArgs wa;
    wa.s[0] = d_in[6];  wa.d[0] = WpgT;              wa.R[0] = 512; wa.C[0] = 256;
    wa.s[1] = d_in[2];  wa.d[1] = WpgT + 256 * 512;  wa.R[1] = 512; wa.C[1] = 256;
    wa.s[2] = d_in[4];  wa.d[2] = WtgT;              wa.R[2] = 512; wa.C[2] = 256;
    wa.s[3] = d_in[2];  wa.d[3] = WtgT + 256 * 512;  wa.R[3] = 512; wa.C[3] = 256;
    wa.s[4] = d_in[8];  wa.d[4] = WwT;               wa.R[4] = 256; wa.C[4] = 512;
    wa.s[5] = d_in[14]; wa.d[5] = WqT;               wa.R[5] = 256; wa.C[5] = 512;

    // ONE canon launch: activations + weights-T + small vectors + flag publish
    canon_all<<<4609, 256, 0, stream>>>(d_in[0], detect_c, d_in[1], aim_c, wa, va, flag);

    const dim3 blk(256);
    const ushort_t* np = nullptr;
    ushort_t* npm = nullptr;

    // merged convs (64-row tiles, 2560 blocks): phi/theta + phiT/d_xT + thetaT/a_xT
    {
        GP2 g;
        g.g[0] = GP{detect_c, WpgT, phi, PT, bpg_c, np, np, np, np, np,
                    0, 0, 0, 0, 512, 512, 512, 256, 256, 32768, 30, 1.f};
        g.g[1] = GP{aim_c, WtgT, theta, TT, btg_c, np, np, np, np, np,
                    0, 0, 0, 0, 512, 512, 512, 256, 256, 8192, 30, 1.f};
        gemm_nt64<EPI_BIAS, false, true, false><<<dim3(4, 640, 1), blk, 0, stream>>>(
            g, 512, flag);
    }

    // merged split-K partials, 16-way, bf16 partial stores (128-tile template):
    // G1 (bz<128, K-chunk 256) + G2 (K-chunk 64). 1024 workgroups.
    {
        GP2 g;
        g.g[0] = GP{phiT, d_xT, P1, npm, np, np, np, np, np, np,
                    0, 256, 256, 65536, 256, 32768, 32768, 256, BIGN, 0, 30, 1.f};
        g.g[1] = GP{thetaT, a_xT, P2, npm, np, np, np, np, np, np,
                    0, 64, 64, 65536, 64, 8192, 8192, 256, BIGN, 0, 30, 1.f};
        gemm_nt<EPI_PART, false, false, true><<<dim3(2, 2, 256), blk, 0, stream>>>(
            g, BIGN, 128, flag);
    }

    // reduce 16 bf16 partial slices -> plain bf16 G (scale folded): 512 blocks
    reduce_g_kernel<<<512, blk, 0, stream>>>(P1, P2, G1, G2);

    // tiny per-batch M = G · W^T, stored transposed (CT path): 128 blocks
    {
        GP2 g;
        g.g[0] = GP{G1, WwT, npm, M1T, np, np, np, np, np, np,
                    0, 65536, 0, 131072, 256, 256, 256, 512, 0, 256, 30, 1.f};
        g.g[1] = GP{G2, WqT, npm, M2T, np, np, np, np, np, np,
                    0, 65536, 0, 131072, 256, 256, 256, 512, 0, 256, 30, 1.f};
        gemm_nt<EPI_SCALE, false, true, false><<<dim3(4, 2, 16), blk, 0, stream>>>(
            g, BIGN, 8, flag);
    }

    // outputs (64-row tiles, 2560 blocks): out1 = BN(phi·M2[b]+bq)+detect ;
    // out0 = BN(theta·M1[b]+bw)+aim. Per-batch M panel via by>>bshift.
    {
        GP2 g;
        g.g[0] = GP{phi, M2T, d_out, npm, bq_c, gq_c, betq_c, mq_c, vq_c, detect_c,
                    8192L * 512, 0, 131072, 0, 256, 256, 256, 512, BIGN, 0, 6, 1.f};
        g.g[1] = GP{theta, M1T, d_out, npm, bw_c, gw_c, betw_c, mw_c, vw_c, aim_c,
                    0, 0, 131072, 0, 256, 256, 256, 512, BIGN, 0, 4, 1.f};
        gemm_nt64<EPI_BN, true, false, true><<<dim3(4, 640, 1), blk, 0, stream>>>(
            g, 512, flag);
    }
}